// Round 4
// baseline (231.159 us; speedup 1.0000x reference)
//
#include <hip/hip_runtime.h>

#define SDIM 14
#define L_COORD 5.0f
#define L_NOOBJ 0.5f
#define BATCH 4096
#define CELLS (BATCH * SDIM * SDIM)   // 802816
#define BLOCK 256
#define CPB 256                       // cells per block
#define NBLOCKS (CELLS / CPB)         // 3136
#define BSTR 11                       // box row stride (pad 10 -> 11, breaks pow2 conflicts)

// Single-pass, float2-granular streaming (each aligned float2 lies wholly in one
// cell since 30 is even): box channels (0..9) scatter to LDS; class channels
// (10..29) reduce in-stream into per-cell LDS accumulator (exact: obj==T[4] is
// 0/1 and is applied in the epilogue). LDS = 23.6 KB -> 6 blocks/CU.
__global__ __launch_bounds__(BLOCK) void yolo_loss(
    const float* __restrict__ pred, const float* __restrict__ targ,
    float* __restrict__ out) {
    __shared__ float bP[CPB * BSTR];   // 2816 floats
    __shared__ float bT[CPB * BSTR];
    __shared__ float cls[CPB];
    __shared__ float wsum[BLOCK / 64];

    const int tid = threadIdx.x;
    cls[tid] = 0.0f;
    __syncthreads();

    // ---- streaming: 15 float2 PAIRS per thread (3840 float2 per tensor/block) ----
    const size_t base2 = (size_t)blockIdx.x * (CPB * 30 / 2);
    const float2* p2 = reinterpret_cast<const float2*>(pred) + base2;
    const float2* t2 = reinterpret_cast<const float2*>(targ) + base2;

#pragma unroll
    for (int j = 0; j < 15; ++j) {
        const int idx = tid + j * BLOCK;       // 0..3839
        const float2 pv = p2[idx];
        const float2 tv = t2[idx];
        const int e0 = idx * 2;                // even element offset in block span
        const int cell = e0 / 30;              // 0..255 (magic-mul)
        const int ch = e0 - cell * 30;         // even, 0..28; float2 never straddles a cell
        if (ch < 10) {                         // both elements are box channels
            const int o = cell * BSTR + ch;
            bP[o] = pv.x; bP[o + 1] = pv.y;
            bT[o] = tv.x; bT[o + 1] = tv.y;
        } else {                               // both elements are class channels
            const float d0 = pv.x - tv.x;
            const float d1 = pv.y - tv.y;
            atomicAdd(&cls[cell], d0 * d0 + d1 * d1);
        }
    }
    __syncthreads();

    // ---- per-cell epilogue: thread tid owns local cell tid ----
    const float* P = bP + tid * BSTR;
    const float* T = bT + tid * BSTR;
    const float obj = T[4];            // exactly 0.0 or 1.0
    const float noobj = 1.0f - obj;

    const float invS = 1.0f / (float)SDIM;
    const float t1x = T[0] * invS - T[2] * 0.5f;
    const float t1y = T[1] * invS - T[3] * 0.5f;
    const float t2x = T[0] * invS + T[2] * 0.5f;
    const float t2y = T[1] * invS + T[3] * 0.5f;
    const float area_t = (t2x - t1x) * (t2y - t1y);

    float iou0 = 0.0f, iou1 = 0.0f;
#pragma unroll
    for (int k = 0; k < 2; ++k) {
        const float bx = P[5 * k + 0], by = P[5 * k + 1];
        const float bw = P[5 * k + 2], bh = P[5 * k + 3];
        const float p1x = bx * invS - bw * 0.5f;
        const float p1y = by * invS - bh * 0.5f;
        const float p2x = bx * invS + bw * 0.5f;
        const float p2y = by * invS + bh * 0.5f;
        const float ltx = fmaxf(p1x, t1x), lty = fmaxf(p1y, t1y);
        const float rbx = fminf(p2x, t2x), rby = fminf(p2y, t2y);
        const float wx = fmaxf(rbx - ltx, 0.0f);
        const float wy = fmaxf(rby - lty, 0.0f);
        const float inter = wx * wy;
        const float area_p = (p2x - p1x) * (p2y - p1y);  // == bw*bh > 0
        const float v = inter / (area_p + area_t - inter);
        if (k == 0) iou0 = v; else iou1 = v;
    }
    const bool pick1 = (iou0 <= iou1);
    const float iou_best = pick1 ? iou1 : iou0;
    const float psx = pick1 ? P[5] : P[0];
    const float psy = pick1 ? P[6] : P[1];
    const float psw = pick1 ? P[7] : P[2];
    const float psh = pick1 ? P[8] : P[3];
    const float psc = pick1 ? P[9] : P[4];
    const float tsx = pick1 ? T[5] : T[0];
    const float tsy = pick1 ? T[6] : T[1];
    const float tsw = pick1 ? T[7] : T[2];
    const float tsh = pick1 ? T[8] : T[3];

    const float dx = psx - tsx, dy = psy - tsy;
    const float dw = sqrtf(psw) - sqrtf(tsw);
    const float dh = sqrtf(psh) - sqrtf(tsh);
    const float reg = dx * dx + dy * dy + dw * dw + dh * dh;
    const float dconf = psc - iou_best;
    const float d4 = P[4] - T[4];
    const float d9 = P[9] - T[9];

    float loss = obj * (cls[tid] + L_COORD * reg + dconf * dconf)
               + L_NOOBJ * noobj * (d4 * d4 + d9 * d9);

    // ---- wave shuffle reduction -> block sum -> one global atomic ----
#pragma unroll
    for (int off = 32; off > 0; off >>= 1)
        loss += __shfl_down(loss, off, 64);
    const int lane = tid & 63;
    const int wave = tid >> 6;
    if (lane == 0) wsum[wave] = loss;
    __syncthreads();
    if (tid == 0) {
        const float bsum = wsum[0] + wsum[1] + wsum[2] + wsum[3];
        atomicAdd(out, bsum * (1.0f / (float)BATCH));
    }
}

extern "C" void kernel_launch(void* const* d_in, const int* in_sizes, int n_in,
                              void* d_out, int out_size, void* d_ws, size_t ws_size,
                              hipStream_t stream) {
    const float* pred = (const float*)d_in[0];
    const float* targ = (const float*)d_in[1];
    float* out = (float*)d_out;

    hipMemsetAsync(out, 0, sizeof(float), stream);   // capturable memset node
    yolo_loss<<<NBLOCKS, BLOCK, 0, stream>>>(pred, targ, out);
}

// Round 5
// 214.329 us; speedup vs baseline: 1.0785x; 1.0785x over previous
//
#include <hip/hip_runtime.h>

#define SDIM 14
#define L_COORD 5.0f
#define L_NOOBJ 0.5f
#define BATCH 4096
#define CELLS (BATCH * SDIM * SDIM)   // 802816
#define BLOCK 256
#define CPB 256                       // cells per block
#define NBLOCKS (CELLS / CPB)         // 3136
#define BSTR 11                       // box row stride (pad 10 -> 11)

// Single-pass. Streaming phase PRELOADS all 30 float2 per thread into register
// arrays with two uniform unrolled load loops (clustered global_load_dwordx2,
// ~30 in flight -> latency fully hidden), THEN scatters box channels to LDS and
// reduces class channels via per-cell LDS atomics. Epilogue per cell from LDS.
__global__ __launch_bounds__(BLOCK, 4) void yolo_loss(
    const float* __restrict__ pred, const float* __restrict__ targ,
    float* __restrict__ out) {
    __shared__ float bP[CPB * BSTR];   // 2816 floats
    __shared__ float bT[CPB * BSTR];
    __shared__ float cls[CPB];
    __shared__ float wsum[BLOCK / 64];

    const int tid = threadIdx.x;
    cls[tid] = 0.0f;
    __syncthreads();

    const size_t base2 = (size_t)blockIdx.x * (CPB * 30 / 2);
    const float2* p2 = reinterpret_cast<const float2*>(pred) + base2;
    const float2* t2 = reinterpret_cast<const float2*>(targ) + base2;

    // ---- phase 1: clustered loads into registers (no branches between) ----
    float2 pv[15], tv[15];
#pragma unroll
    for (int j = 0; j < 15; ++j) pv[j] = p2[tid + j * BLOCK];
#pragma unroll
    for (int j = 0; j < 15; ++j) tv[j] = t2[tid + j * BLOCK];

    // ---- phase 2: scatter/reduce from registers ----
#pragma unroll
    for (int j = 0; j < 15; ++j) {
        const int idx = tid + j * BLOCK;       // 0..3839
        const int e0 = idx * 2;                // even element offset in block span
        const int cell = e0 / 30;              // 0..255 (magic-mul)
        const int ch = e0 - cell * 30;         // even; float2 never straddles a cell
        if (ch < 10) {                         // both elements box channels
            const int o = cell * BSTR + ch;
            bP[o] = pv[j].x; bP[o + 1] = pv[j].y;
            bT[o] = tv[j].x; bT[o + 1] = tv[j].y;
        } else {                               // both elements class channels
            const float d0 = pv[j].x - tv[j].x;
            const float d1 = pv[j].y - tv[j].y;
            atomicAdd(&cls[cell], d0 * d0 + d1 * d1);
        }
    }
    __syncthreads();

    // ---- per-cell epilogue: thread tid owns local cell tid ----
    const float* P = bP + tid * BSTR;
    const float* T = bT + tid * BSTR;
    const float obj = T[4];            // exactly 0.0 or 1.0
    const float noobj = 1.0f - obj;

    const float invS = 1.0f / (float)SDIM;
    const float t1x = T[0] * invS - T[2] * 0.5f;
    const float t1y = T[1] * invS - T[3] * 0.5f;
    const float t2x = T[0] * invS + T[2] * 0.5f;
    const float t2y = T[1] * invS + T[3] * 0.5f;
    const float area_t = (t2x - t1x) * (t2y - t1y);

    float iou0 = 0.0f, iou1 = 0.0f;
#pragma unroll
    for (int k = 0; k < 2; ++k) {
        const float bx = P[5 * k + 0], by = P[5 * k + 1];
        const float bw = P[5 * k + 2], bh = P[5 * k + 3];
        const float p1x = bx * invS - bw * 0.5f;
        const float p1y = by * invS - bh * 0.5f;
        const float p2x = bx * invS + bw * 0.5f;
        const float p2y = by * invS + bh * 0.5f;
        const float ltx = fmaxf(p1x, t1x), lty = fmaxf(p1y, t1y);
        const float rbx = fminf(p2x, t2x), rby = fminf(p2y, t2y);
        const float wx = fmaxf(rbx - ltx, 0.0f);
        const float wy = fmaxf(rby - lty, 0.0f);
        const float inter = wx * wy;
        const float area_p = (p2x - p1x) * (p2y - p1y);
        const float v = inter / (area_p + area_t - inter);
        if (k == 0) iou0 = v; else iou1 = v;
    }
    const bool pick1 = (iou0 <= iou1);
    const float iou_best = pick1 ? iou1 : iou0;
    const float psx = pick1 ? P[5] : P[0];
    const float psy = pick1 ? P[6] : P[1];
    const float psw = pick1 ? P[7] : P[2];
    const float psh = pick1 ? P[8] : P[3];
    const float psc = pick1 ? P[9] : P[4];
    const float tsx = pick1 ? T[5] : T[0];
    const float tsy = pick1 ? T[6] : T[1];
    const float tsw = pick1 ? T[7] : T[2];
    const float tsh = pick1 ? T[8] : T[3];

    const float dx = psx - tsx, dy = psy - tsy;
    const float dw = sqrtf(psw) - sqrtf(tsw);
    const float dh = sqrtf(psh) - sqrtf(tsh);
    const float reg = dx * dx + dy * dy + dw * dw + dh * dh;
    const float dconf = psc - iou_best;
    const float d4 = P[4] - T[4];
    const float d9 = P[9] - T[9];

    float loss = obj * (cls[tid] + L_COORD * reg + dconf * dconf)
               + L_NOOBJ * noobj * (d4 * d4 + d9 * d9);

    // ---- wave shuffle reduction -> block sum -> one global atomic ----
#pragma unroll
    for (int off = 32; off > 0; off >>= 1)
        loss += __shfl_down(loss, off, 64);
    const int lane = tid & 63;
    const int wave = tid >> 6;
    if (lane == 0) wsum[wave] = loss;
    __syncthreads();
    if (tid == 0) {
        const float bsum = wsum[0] + wsum[1] + wsum[2] + wsum[3];
        atomicAdd(out, bsum * (1.0f / (float)BATCH));
    }
}

extern "C" void kernel_launch(void* const* d_in, const int* in_sizes, int n_in,
                              void* d_out, int out_size, void* d_ws, size_t ws_size,
                              hipStream_t stream) {
    const float* pred = (const float*)d_in[0];
    const float* targ = (const float*)d_in[1];
    float* out = (float*)d_out;

    hipMemsetAsync(out, 0, sizeof(float), stream);   // capturable memset node
    yolo_loss<<<NBLOCKS, BLOCK, 0, stream>>>(pred, targ, out);
}

// Round 6
// 206.086 us; speedup vs baseline: 1.1217x; 1.0400x over previous
//
#include <hip/hip_runtime.h>

#define SDIM 14
#define L_COORD 5.0f
#define L_NOOBJ 0.5f
#define BATCH 4096
#define CELLS (BATCH * SDIM * SDIM)   // 802816
#define BLOCK 256
#define CPB 256                       // cells per block
#define NBLOCKS (CELLS / CPB)         // 3136
#define BLK_F 7680                    // floats per tensor per block (256*30)

// Staging via async direct-to-LDS DMA (global_load_lds, width=16): each wave
// issues 15 back-to-back 1-KB DMA ops (no VGPR round-trip -> compiler cannot
// sink/serialize them), __syncthreads() drains vmcnt. LDS layout is flat
// (DMA requires wave-uniform base + lane*16). Epilogue reads per-cell
// stride-30 rows from LDS (4-way bank conflict, negligible vs stream time).
__global__ __launch_bounds__(BLOCK) void yolo_loss(
    const float* __restrict__ pred, const float* __restrict__ targ,
    float* __restrict__ out) {
    __shared__ float s[2 * BLK_F];     // 61440 B: [0,7680)=pred span, [7680,15360)=targ
    __shared__ float wsum[BLOCK / 64];

    const int tid = threadIdx.x;
    const int wave = tid >> 6;
    const int lane = tid & 63;
    const size_t blockbase = (size_t)blockIdx.x * BLK_F;

    // ---- 60 chunks of 1024 B; wave w takes chunks w, w+4, ..., w+56 ----
#pragma unroll
    for (int i = 0; i < 15; ++i) {
        const int c = wave + i * 4;    // 0..59, wave-uniform
        const float* gsrc = (c < 30)
            ? (pred + blockbase + (size_t)c * 256)
            : (targ + blockbase + (size_t)(c - 30) * 256);
        __builtin_amdgcn_global_load_lds(
            (const __attribute__((address_space(1))) void*)(gsrc + lane * 4),
            (__attribute__((address_space(3))) void*)(s + c * 256),
            16, 0, 0);
    }
    __syncthreads();   // drains vmcnt(0) before barrier -> LDS valid

    // ---- per-cell epilogue: thread tid owns local cell tid ----
    const float* P = s + tid * 30;
    const float* T = s + BLK_F + tid * 30;

    const float obj = T[4];            // exactly 0.0 or 1.0
    const float noobj = 1.0f - obj;

    float cls = 0.0f;
#pragma unroll
    for (int c = 10; c < 30; ++c) { const float d = P[c] - T[c]; cls += d * d; }

    const float invS = 1.0f / (float)SDIM;
    const float t1x = T[0] * invS - T[2] * 0.5f;
    const float t1y = T[1] * invS - T[3] * 0.5f;
    const float t2x = T[0] * invS + T[2] * 0.5f;
    const float t2y = T[1] * invS + T[3] * 0.5f;
    const float area_t = (t2x - t1x) * (t2y - t1y);

    float iou0 = 0.0f, iou1 = 0.0f;
#pragma unroll
    for (int k = 0; k < 2; ++k) {
        const float bx = P[5 * k + 0], by = P[5 * k + 1];
        const float bw = P[5 * k + 2], bh = P[5 * k + 3];
        const float p1x = bx * invS - bw * 0.5f;
        const float p1y = by * invS - bh * 0.5f;
        const float p2x = bx * invS + bw * 0.5f;
        const float p2y = by * invS + bh * 0.5f;
        const float ltx = fmaxf(p1x, t1x), lty = fmaxf(p1y, t1y);
        const float rbx = fminf(p2x, t2x), rby = fminf(p2y, t2y);
        const float wx = fmaxf(rbx - ltx, 0.0f);
        const float wy = fmaxf(rby - lty, 0.0f);
        const float inter = wx * wy;
        const float area_p = (p2x - p1x) * (p2y - p1y);
        const float v = inter / (area_p + area_t - inter);
        if (k == 0) iou0 = v; else iou1 = v;
    }
    const bool pick1 = (iou0 <= iou1);
    const float iou_best = pick1 ? iou1 : iou0;
    const float psx = pick1 ? P[5] : P[0];
    const float psy = pick1 ? P[6] : P[1];
    const float psw = pick1 ? P[7] : P[2];
    const float psh = pick1 ? P[8] : P[3];
    const float psc = pick1 ? P[9] : P[4];
    const float tsx = pick1 ? T[5] : T[0];
    const float tsy = pick1 ? T[6] : T[1];
    const float tsw = pick1 ? T[7] : T[2];
    const float tsh = pick1 ? T[8] : T[3];

    const float dx = psx - tsx, dy = psy - tsy;
    const float dw = sqrtf(psw) - sqrtf(tsw);
    const float dh = sqrtf(psh) - sqrtf(tsh);
    const float reg = dx * dx + dy * dy + dw * dw + dh * dh;
    const float dconf = psc - iou_best;
    const float d4 = P[4] - T[4];
    const float d9 = P[9] - T[9];

    float loss = obj * (cls + L_COORD * reg + dconf * dconf)
               + L_NOOBJ * noobj * (d4 * d4 + d9 * d9);

    // ---- wave shuffle reduction -> block sum -> one global atomic ----
#pragma unroll
    for (int off = 32; off > 0; off >>= 1)
        loss += __shfl_down(loss, off, 64);
    if (lane == 0) wsum[wave] = loss;
    __syncthreads();
    if (tid == 0) {
        const float bsum = wsum[0] + wsum[1] + wsum[2] + wsum[3];
        atomicAdd(out, bsum * (1.0f / (float)BATCH));
    }
}

extern "C" void kernel_launch(void* const* d_in, const int* in_sizes, int n_in,
                              void* d_out, int out_size, void* d_ws, size_t ws_size,
                              hipStream_t stream) {
    const float* pred = (const float*)d_in[0];
    const float* targ = (const float*)d_in[1];
    float* out = (float*)d_out;

    hipMemsetAsync(out, 0, sizeof(float), stream);   // capturable memset node
    yolo_loss<<<NBLOCKS, BLOCK, 0, stream>>>(pred, targ, out);
}